// Round 5
// baseline (800.131 us; speedup 1.0000x reference)
//
#include <hip/hip_runtime.h>
#include <math.h>

#define BB 8
#define CC 128
#define HH 64
#define WW 64
#define NPTS 9
#define OUTC 256
#define HW (HH*WW)
#define KTOT (CC*NPTS)   // 1152
#define BK 288           // 32 channels * 9 taps per K-chunk
#define AP 290           // Atile row in bf16 elems: 580 B = 145 words (ODD -> conflict-free)
#define WROWS 6          // x row window: global rows h-2 .. h+3
#define WINF (WROWS*WW)  // 384 floats per staged channel

typedef __attribute__((ext_vector_type(8))) short bf16x8;
typedef __attribute__((ext_vector_type(4))) float f32x4;

__device__ __forceinline__ unsigned short f2bf(float f) {
    unsigned int u = __builtin_bit_cast(unsigned int, f);
    unsigned int r = (u + 0x7FFFu + ((u >> 16) & 1u)) >> 16;   // RNE
    return (unsigned short)r;
}

__device__ __forceinline__ bf16x8 loadw8(const float* p) {
    const float4* p4 = (const float4*)p;
    float4 lo = p4[0], hi = p4[1];
    bf16x8 r;
    r[0] = (short)f2bf(lo.x); r[1] = (short)f2bf(lo.y);
    r[2] = (short)f2bf(lo.z); r[3] = (short)f2bf(lo.w);
    r[4] = (short)f2bf(hi.x); r[5] = (short)f2bf(hi.y);
    r[6] = (short)f2bf(hi.z); r[7] = (short)f2bf(hi.w);
    return r;
}

// T14 async-stage split: issue global loads for one 8-channel / 6-row window
// phase into registers (issue_stage), commit to LDS later (commit_stage).
struct PF { float4 v0, v1, v2; };

__device__ __forceinline__ PF issue_stage(const float* __restrict__ xb,
                                          int h, int cb, int s, int tid) {
    int c8 = tid >> 5, sub = tid & 31;
    const float* xc = xb + (size_t)(cb * 32 + s * 8 + c8) * HW;
    float4 z = make_float4(0.f, 0.f, 0.f, 0.f);
    PF p;
    int e0 = sub * 4;
    int gr0 = h - 2 + (e0 >> 6);
    int gr1 = h - 2 + ((e0 + 128) >> 6);
    int gr2 = h - 2 + ((e0 + 256) >> 6);
    p.v0 = (gr0 >= 0 && gr0 < HH) ? *(const float4*)(xc + gr0 * WW + (e0 & 63)) : z;
    p.v1 = (gr1 >= 0 && gr1 < HH) ? *(const float4*)(xc + gr1 * WW + ((e0 + 128) & 63)) : z;
    p.v2 = (gr2 >= 0 && gr2 < HH) ? *(const float4*)(xc + gr2 * WW + ((e0 + 256) & 63)) : z;
    return p;
}

__device__ __forceinline__ void commit_stage(float* winp, const PF& p, int tid) {
    int c8 = tid >> 5, sub = tid & 31;
    float* wr = winp + c8 * WINF + sub * 4;
    *(float4*)(wr)       = p.v0;
    *(float4*)(wr + 128) = p.v1;
    *(float4*)(wr + 256) = p.v2;
}

__global__ __launch_bounds__(256, 3) void fused_kernel(
    const float* __restrict__ x,
    const float* __restrict__ w_offset, const float* __restrict__ b_offset,
    const float* __restrict__ w_mask,   const float* __restrict__ b_mask,
    const float* __restrict__ w_conv,
    const float* __restrict__ bn_gamma, const float* __restrict__ bn_beta,
    const float* __restrict__ bn_mean,  const float* __restrict__ bn_var,
    float* __restrict__ out)
{
    __shared__ unsigned short Atile[64][AP];   // 37120 B
    __shared__ float ov[8 * WINF];             // 12288 B: win, overlaid px/py/m
    // total 48.3 KB -> 3 blocks/CU

    int blk = blockIdx.x;
    int b = blk >> 6, h = blk & 63;
    int tid  = threadIdx.x;
    int lane = tid & 63;
    int wv   = __builtin_amdgcn_readfirstlane(tid >> 6);  // wave 0..3
    int l15  = lane & 15;
    int kg   = lane >> 4;
    int spix = lane;                                      // pixel for build phases

    const float* xb = x + (size_t)b * CC * HW;

    // ================= PASS A: offset/mask conv (M=64,N=32,K=1152) =========
    f32x4 s1acc0 = {0.f, 0.f, 0.f, 0.f};
    f32x4 s1acc1 = {0.f, 0.f, 0.f, 0.f};

    PF pf = issue_stage(xb, h, 0, 0, tid);
    for (int cb = 0; cb < 4; ++cb) {
        for (int s = 0; s < 4; ++s) {
            __syncthreads();                 // win readers / Atile readers done
            commit_stage(ov, pf, tid);
            __syncthreads();                 // win ready
            {   // prefetch next phase (wraps into pass B's (0,0) at the end)
                int ns = s + 1, nc = cb;
                if (ns == 4) { ns = 0; ++nc; }
                if (nc == 4) { nc = 0; ns = 0; }
                pf = issue_stage(xb, h, nc, ns, tid);
            }
            #pragma unroll
            for (int ci = 0; ci < 2; ++ci) {
                int wc  = wv * 2 + ci;
                int c32 = s * 8 + wc;
                const float* wrow = ov + wc * WINF;
                #pragma unroll
                for (int ky = 0; ky < 3; ++ky) {
                    #pragma unroll
                    for (int kx = 0; kx < 3; ++kx) {
                        int col  = spix + kx - 1;
                        int colc = min(max(col, 0), WW - 1);
                        float v = wrow[(ky + 1) * WW + colc];  // row h+ky-1
                        v = (col >= 0 && col < WW) ? v : 0.f;
                        Atile[spix][c32 * 9 + ky * 3 + kx] = f2bf(v);
                    }
                }
            }
        }
        __syncthreads();                     // Atile complete (all win reads done)
        for (int q = 0; q < 9; ++q) {
            int koff  = q * 32 + kg * 8;
            int kglob = cb * BK + koff;
            bf16x8 af = *(const bf16x8*)&Atile[wv * 16 + l15][koff];
            {   // N-frag 0: cols 0..15 of w_offset
                bf16x8 bfr = loadw8(w_offset + (size_t)l15 * KTOT + kglob);
                s1acc0 = __builtin_amdgcn_mfma_f32_16x16x32_bf16(af, bfr, s1acc0, 0, 0, 0);
            }
            {   // N-frag 1: 16,17 w_offset; 18..26 w_mask; 27+ zero
                int nn = 16 + l15;
                const float* wp = (nn < 18)
                    ? (w_offset + (size_t)nn * KTOT + kglob)
                    : (w_mask + (size_t)(nn < 27 ? nn - 18 : 0) * KTOT + kglob);
                bf16x8 bfr = loadw8(wp);
                if (nn >= 27) {
                    #pragma unroll
                    for (int e = 0; e < 8; ++e) bfr[e] = 0;
                }
                s1acc1 = __builtin_amdgcn_mfma_f32_16x16x32_bf16(af, bfr, s1acc1, 0, 0, 0);
            }
        }
    }

    // ---- pass-A epilogue into the overlay (win is dead: all builds done) ---
    // layout: px at ov[0..575], py at ov[576..1151], m at ov[1152..1727]
    #pragma unroll
    for (int f = 0; f < 2; ++f) {
        #pragma unroll
        for (int j = 0; j < 4; ++j) {
            float val = (f == 0) ? s1acc0[j] : s1acc1[j];
            int nn   = f * 16 + l15;
            int pixl = wv * 16 + kg * 4 + j;
            if (nn < 9) {
                ov[nn * 64 + pixl] = val + b_offset[nn] + (float)(nn / 3 - 1) + (float)(h + 1);
            } else if (nn < 18) {
                int n = nn - 9;
                ov[576 + n * 64 + pixl] = val + b_offset[nn] + (float)(n % 3 - 1) + (float)(pixl + 1);
            } else if (nn < 27) {
                int n = nn - 18;
                float sg = val + b_mask[n];
                ov[1152 + n * 64 + pixl] = 1.f / (1.f + expf(-sg));
            }
        }
    }
    __syncthreads();

    // ================= per-thread bilinear params (pixel = spix) ============
    // ok: window offsets into ov; !ok (rare): GLOBAL offsets into xb channel
    // plane — same o/dr/dj algebra, different base.
    float gw[NPTS][4];
    int po[NPTS], pdr[NPTS], pdj[NPTS];
    unsigned okmask = 0;
    #pragma unroll
    for (int n = 0; n < NPTS; ++n) {
        float px = ov[n * 64 + spix];
        float py = ov[576 + n * 64 + spix];
        float m  = ov[1152 + n * 64 + spix];
        float fx = floorf(px), fy = floorf(py);
        float qltx = fminf(fmaxf(fx,       0.f), 65.f);
        float qlty = fminf(fmaxf(fy,       0.f), 65.f);
        float qrbx = fminf(fmaxf(fx + 1.f, 0.f), 65.f);
        float qrby = fminf(fmaxf(fy + 1.f, 0.f), 65.f);
        float pxc  = fminf(fmaxf(px, 0.f), 65.f);
        float pyc  = fminf(fmaxf(py, 0.f), 65.f);
        float glt = (1.f + (qltx - pxc)) * (1.f + (qlty - pyc)) * m;
        float grb = (1.f - (qrbx - pxc)) * (1.f - (qrby - pyc)) * m;
        float glb = (1.f + (qltx - pxc)) * (1.f - (qrby - pyc)) * m;
        float grt = (1.f - (qrbx - pxc)) * (1.f + (qlty - pyc)) * m;
        int i0 = (int)qltx - 1, j0 = (int)qlty - 1;
        int i1 = (int)qrbx - 1, j1 = (int)qrby - 1;
        bool v00 = (i0 >= 0) & (i0 < HH) & (j0 >= 0) & (j0 < WW);
        bool v11 = (i1 >= 0) & (i1 < HH) & (j1 >= 0) & (j1 < WW);
        bool v01 = (i0 >= 0) & (i0 < HH) & (j1 >= 0) & (j1 < WW);
        bool v10 = (i1 >= 0) & (i1 < HH) & (j0 >= 0) & (j0 < WW);
        gw[n][0] = v00 ? glt : 0.f;   // (i0,j0)
        gw[n][1] = v11 ? grb : 0.f;   // (i1,j1)
        gw[n][2] = v01 ? glb : 0.f;   // (i0,j1)
        gw[n][3] = v10 ? grt : 0.f;   // (i1,j0)
        bool okr0 = ((i0 >= h - 2) & (i0 <= h + 3)) | !(v00 | v01);
        bool okr1 = ((i1 >= h - 2) & (i1 <= h + 3)) | !(v11 | v10);
        bool ok = okr0 & okr1;
        if (ok) okmask |= (1u << n);
        int r0w = min(max(i0 - (h - 2), 0), WROWS - 1);
        int r1w = min(max(i1 - (h - 2), 0), WROWS - 1);
        int r0g = min(max(i0, 0), HH - 1);
        int r1g = min(max(i1, 0), HH - 1);
        int j0c = min(max(j0, 0), WW - 1);
        int j1c = min(max(j1, 0), WW - 1);
        po[n]  = ok ? (r0w * WW + j0c) : (r0g * WW + j0c);
        pdr[n] = ok ? (r1w - r0w) * WW : (r1g - r0g) * WW;
        pdj[n] = j1c - j0c;
    }

    // ================= PASS B: main GEMM (M=64, N=256, K=1152) ==============
    f32x4 acc[4][4];
    #pragma unroll
    for (int mi = 0; mi < 4; ++mi)
        #pragma unroll
        for (int ni = 0; ni < 4; ++ni)
            acc[mi][ni] = (f32x4){0.f, 0.f, 0.f, 0.f};

    int oc0 = wv * 64;

    for (int cb = 0; cb < 4; ++cb) {
        for (int s = 0; s < 4; ++s) {
            __syncthreads();                 // param/win readers done (s==0: +MFMA Atile readers)
            commit_stage(ov, pf, tid);
            __syncthreads();                 // win ready
            {
                int ns = s + 1, nc = cb;
                if (ns == 4) { ns = 0; ++nc; }
                if (nc < 4) pf = issue_stage(xb, h, nc, ns, tid);
            }
            #pragma unroll
            for (int ci = 0; ci < 2; ++ci) {
                int wc  = wv * 2 + ci;
                int c32 = s * 8 + wc;
                const float* winc = ov + wc * WINF;
                const float* xg   = xb + (size_t)(cb * 32 + c32) * HW;
                #pragma unroll
                for (int n = 0; n < NPTS; ++n) {
                    int o = po[n], d1 = pdr[n], d2 = pdj[n];
                    float x00, x01, x10, x11;
                    if (okmask & (1u << n)) {
                        x00 = winc[o];
                        x01 = winc[o + d2];
                        x10 = winc[o + d1];
                        x11 = winc[o + d1 + d2];
                    } else {                 // rare: corner outside 6-row window
                        x00 = xg[o];
                        x01 = xg[o + d2];
                        x10 = xg[o + d1];
                        x11 = xg[o + d1 + d2];
                    }
                    float v =       gw[n][0] * x00;
                    v = fmaf(gw[n][1], x11, v);
                    v = fmaf(gw[n][2], x01, v);
                    v = fmaf(gw[n][3], x10, v);
                    Atile[spix][c32 * 9 + n] = f2bf(v);
                }
            }
        }
        __syncthreads();                     // Atile complete
        for (int q = 0; q < 9; ++q) {
            int koff = q * 32 + kg * 8;
            bf16x8 af[4];
            #pragma unroll
            for (int mi = 0; mi < 4; ++mi)
                af[mi] = *(const bf16x8*)&Atile[mi * 16 + l15][koff];
            #pragma unroll
            for (int ni = 0; ni < 4; ++ni) {
                int oc = oc0 + ni * 16 + l15;
                bf16x8 bfr = loadw8(w_conv + (size_t)oc * KTOT + cb * BK + koff);
                #pragma unroll
                for (int mi = 0; mi < 4; ++mi)
                    acc[mi][ni] = __builtin_amdgcn_mfma_f32_16x16x32_bf16(af[mi], bfr, acc[mi][ni], 0, 0, 0);
            }
        }
    }

    // ================= epilogue: BN + ReLU, float4 stores ===================
    #pragma unroll
    for (int ni = 0; ni < 4; ++ni) {
        int oc = oc0 + ni * 16 + l15;
        float inv   = 1.f / sqrtf(bn_var[oc] + 1e-5f);
        float scale = bn_gamma[oc] * inv;
        float shift = bn_beta[oc] - bn_mean[oc] * scale;
        float* op = out + ((size_t)b * OUTC + oc) * HW + h * WW + kg * 4;
        #pragma unroll
        for (int mi = 0; mi < 4; ++mi) {
            f32x4 o4;
            #pragma unroll
            for (int j = 0; j < 4; ++j) {
                float v = fmaf(acc[mi][ni][j], scale, shift);
                o4[j] = v > 0.f ? v : 0.f;
            }
            *(f32x4*)(op + mi * 16) = o4;
        }
    }
}

extern "C" void kernel_launch(void* const* d_in, const int* in_sizes, int n_in,
                              void* d_out, int out_size, void* d_ws, size_t ws_size,
                              hipStream_t stream) {
    (void)in_sizes; (void)n_in; (void)out_size; (void)d_ws; (void)ws_size;
    const float* x        = (const float*)d_in[0];
    const float* w_offset = (const float*)d_in[1];
    const float* b_offset = (const float*)d_in[2];
    const float* w_mask   = (const float*)d_in[3];
    const float* b_mask   = (const float*)d_in[4];
    const float* w_conv   = (const float*)d_in[5];
    const float* bn_gamma = (const float*)d_in[6];
    const float* bn_beta  = (const float*)d_in[7];
    const float* bn_mean  = (const float*)d_in[8];
    const float* bn_var   = (const float*)d_in[9];
    float* out = (float*)d_out;

    fused_kernel<<<BB * HH, 256, 0, stream>>>(x, w_offset, b_offset, w_mask, b_mask,
                                              w_conv, bn_gamma, bn_beta, bn_mean, bn_var,
                                              out);
}

// Round 6
// 501.052 us; speedup vs baseline: 1.5969x; 1.5969x over previous
//
#include <hip/hip_runtime.h>
#include <math.h>

#define BB 8
#define CC 128
#define HH 64
#define WW 64
#define NPTS 9
#define OUTC 256
#define HW (HH*WW)
#define KTOT (CC*NPTS)   // 1152
#define BK 288           // 32 channels * 9 taps per K-chunk
#define AP 290           // Atile row in bf16 elems: 580 B = 145 words (ODD -> 2-way=free)
#define WROWS 6          // x row window: global rows h-2 .. h+3
#define WINF (WROWS*WW)  // 384 floats per staged channel

typedef __attribute__((ext_vector_type(8))) short bf16x8;
typedef __attribute__((ext_vector_type(4))) float f32x4;

__device__ __forceinline__ unsigned short f2bf(float f) {
    unsigned int u = __builtin_bit_cast(unsigned int, f);
    unsigned int r = (u + 0x7FFFu + ((u >> 16) & 1u)) >> 16;   // RNE
    return (unsigned short)r;
}

__device__ __forceinline__ bf16x8 loadw8(const float* p) {
    const float4* p4 = (const float4*)p;
    float4 lo = p4[0], hi = p4[1];
    bf16x8 r;
    r[0] = (short)f2bf(lo.x); r[1] = (short)f2bf(lo.y);
    r[2] = (short)f2bf(lo.z); r[3] = (short)f2bf(lo.w);
    r[4] = (short)f2bf(hi.x); r[5] = (short)f2bf(hi.y);
    r[6] = (short)f2bf(hi.z); r[7] = (short)f2bf(hi.w);
    return r;
}

// T14 async-stage split: issue global loads for one 8-channel / 6-row window
// phase into registers (issue_stage), commit to LDS later (commit_stage).
struct PF { float4 v0, v1, v2; };

__device__ __forceinline__ PF issue_stage(const float* __restrict__ xb,
                                          int h, int cb, int s, int tid) {
    int c8 = tid >> 5, sub = tid & 31;
    const float* xc = xb + (size_t)(cb * 32 + s * 8 + c8) * HW;
    float4 z = make_float4(0.f, 0.f, 0.f, 0.f);
    PF p;
    int e0 = sub * 4;
    int gr0 = h - 2 + (e0 >> 6);
    int gr1 = h - 2 + ((e0 + 128) >> 6);
    int gr2 = h - 2 + ((e0 + 256) >> 6);
    p.v0 = (gr0 >= 0 && gr0 < HH) ? *(const float4*)(xc + gr0 * WW + (e0 & 63)) : z;
    p.v1 = (gr1 >= 0 && gr1 < HH) ? *(const float4*)(xc + gr1 * WW + ((e0 + 128) & 63)) : z;
    p.v2 = (gr2 >= 0 && gr2 < HH) ? *(const float4*)(xc + gr2 * WW + ((e0 + 256) & 63)) : z;
    return p;
}

__device__ __forceinline__ void commit_stage(float* winp, const PF& p, int tid) {
    int c8 = tid >> 5, sub = tid & 31;
    float* wr = winp + c8 * WINF + sub * 4;
    *(float4*)(wr)       = p.v0;
    *(float4*)(wr + 128) = p.v1;
    *(float4*)(wr + 256) = p.v2;
}

// NOTE: second arg MUST stay 2. (256,3) made the compiler cap VGPRs at 84 ->
// massive scratch spills (R5: FETCH_SIZE 1.3 GB, 800 us). At (256,2) the
// natural allocation (~128-156) is <= 168, so 3 blocks/CU (LDS-limited)
// remains reachable at runtime.
__global__ __launch_bounds__(256, 2) void fused_kernel(
    const float* __restrict__ x,
    const float* __restrict__ w_offset, const float* __restrict__ b_offset,
    const float* __restrict__ w_mask,   const float* __restrict__ b_mask,
    const float* __restrict__ w_conv,
    const float* __restrict__ bn_gamma, const float* __restrict__ bn_beta,
    const float* __restrict__ bn_mean,  const float* __restrict__ bn_var,
    float* __restrict__ out)
{
    __shared__ unsigned short Atile[64][AP];   // 37120 B
    __shared__ float ov[8 * WINF];             // 12288 B: win, overlaid px/py/m
    // total 48.3 KB -> 3 blocks/CU (if VGPR <= 168)

    int blk = blockIdx.x;
    int b = blk >> 6, h = blk & 63;
    int tid  = threadIdx.x;
    int lane = tid & 63;
    int wv   = __builtin_amdgcn_readfirstlane(tid >> 6);  // wave 0..3
    int l15  = lane & 15;
    int kg   = lane >> 4;
    int spix = lane;                                      // pixel for build phases

    const float* xb = x + (size_t)b * CC * HW;

    // ================= PASS A: offset/mask conv (M=64,N=32,K=1152) =========
    f32x4 s1acc0 = {0.f, 0.f, 0.f, 0.f};
    f32x4 s1acc1 = {0.f, 0.f, 0.f, 0.f};

    PF pf = issue_stage(xb, h, 0, 0, tid);
    for (int cb = 0; cb < 4; ++cb) {
        for (int s = 0; s < 4; ++s) {
            __syncthreads();                 // win readers / Atile readers done
            commit_stage(ov, pf, tid);
            __syncthreads();                 // win ready
            {   // prefetch next phase (wraps into pass B's (0,0) at the end)
                int ns = s + 1, nc = cb;
                if (ns == 4) { ns = 0; ++nc; }
                if (nc == 4) { nc = 0; ns = 0; }
                pf = issue_stage(xb, h, nc, ns, tid);
            }
            #pragma unroll
            for (int ci = 0; ci < 2; ++ci) {
                int wc  = wv * 2 + ci;
                int c32 = s * 8 + wc;
                const float* wrow = ov + wc * WINF;
                #pragma unroll
                for (int ky = 0; ky < 3; ++ky) {
                    #pragma unroll
                    for (int kx = 0; kx < 3; ++kx) {
                        int col  = spix + kx - 1;
                        int colc = min(max(col, 0), WW - 1);
                        float v = wrow[(ky + 1) * WW + colc];  // row h+ky-1
                        v = (col >= 0 && col < WW) ? v : 0.f;
                        Atile[spix][c32 * 9 + ky * 3 + kx] = f2bf(v);
                    }
                }
            }
        }
        __syncthreads();                     // Atile complete (all win reads done)
        for (int q = 0; q < 9; ++q) {
            int koff  = q * 32 + kg * 8;
            int kglob = cb * BK + koff;
            bf16x8 af = *(const bf16x8*)&Atile[wv * 16 + l15][koff];
            {   // N-frag 0: cols 0..15 of w_offset
                bf16x8 bfr = loadw8(w_offset + (size_t)l15 * KTOT + kglob);
                s1acc0 = __builtin_amdgcn_mfma_f32_16x16x32_bf16(af, bfr, s1acc0, 0, 0, 0);
            }
            {   // N-frag 1: 16,17 w_offset; 18..26 w_mask; 27+ zero
                int nn = 16 + l15;
                const float* wp = (nn < 18)
                    ? (w_offset + (size_t)nn * KTOT + kglob)
                    : (w_mask + (size_t)(nn < 27 ? nn - 18 : 0) * KTOT + kglob);
                bf16x8 bfr = loadw8(wp);
                if (nn >= 27) {
                    #pragma unroll
                    for (int e = 0; e < 8; ++e) bfr[e] = 0;
                }
                s1acc1 = __builtin_amdgcn_mfma_f32_16x16x32_bf16(af, bfr, s1acc1, 0, 0, 0);
            }
        }
    }

    // ---- pass-A epilogue into the overlay (win is dead: all builds done) ---
    // layout: px at ov[0..575], py at ov[576..1151], m at ov[1152..1727]
    #pragma unroll
    for (int f = 0; f < 2; ++f) {
        #pragma unroll
        for (int j = 0; j < 4; ++j) {
            float val = (f == 0) ? s1acc0[j] : s1acc1[j];
            int nn   = f * 16 + l15;
            int pixl = wv * 16 + kg * 4 + j;
            if (nn < 9) {
                ov[nn * 64 + pixl] = val + b_offset[nn] + (float)(nn / 3 - 1) + (float)(h + 1);
            } else if (nn < 18) {
                int n = nn - 9;
                ov[576 + n * 64 + pixl] = val + b_offset[nn] + (float)(n % 3 - 1) + (float)(pixl + 1);
            } else if (nn < 27) {
                int n = nn - 18;
                float sg = val + b_mask[n];
                ov[1152 + n * 64 + pixl] = 1.f / (1.f + expf(-sg));
            }
        }
    }
    __syncthreads();

    // ================= per-thread bilinear params (pixel = spix) ============
    // ok: window offsets into ov; !ok (rare): GLOBAL offsets into xb channel
    // plane — same o/dr/dj algebra, different base.
    float gw[NPTS][4];
    int po[NPTS], pdr[NPTS], pdj[NPTS];
    unsigned okmask = 0;
    #pragma unroll
    for (int n = 0; n < NPTS; ++n) {
        float px = ov[n * 64 + spix];
        float py = ov[576 + n * 64 + spix];
        float m  = ov[1152 + n * 64 + spix];
        float fx = floorf(px), fy = floorf(py);
        float qltx = fminf(fmaxf(fx,       0.f), 65.f);
        float qlty = fminf(fmaxf(fy,       0.f), 65.f);
        float qrbx = fminf(fmaxf(fx + 1.f, 0.f), 65.f);
        float qrby = fminf(fmaxf(fy + 1.f, 0.f), 65.f);
        float pxc  = fminf(fmaxf(px, 0.f), 65.f);
        float pyc  = fminf(fmaxf(py, 0.f), 65.f);
        float glt = (1.f + (qltx - pxc)) * (1.f + (qlty - pyc)) * m;
        float grb = (1.f - (qrbx - pxc)) * (1.f - (qrby - pyc)) * m;
        float glb = (1.f + (qltx - pxc)) * (1.f - (qrby - pyc)) * m;
        float grt = (1.f - (qrbx - pxc)) * (1.f + (qlty - pyc)) * m;
        int i0 = (int)qltx - 1, j0 = (int)qlty - 1;
        int i1 = (int)qrbx - 1, j1 = (int)qrby - 1;
        bool v00 = (i0 >= 0) & (i0 < HH) & (j0 >= 0) & (j0 < WW);
        bool v11 = (i1 >= 0) & (i1 < HH) & (j1 >= 0) & (j1 < WW);
        bool v01 = (i0 >= 0) & (i0 < HH) & (j1 >= 0) & (j1 < WW);
        bool v10 = (i1 >= 0) & (i1 < HH) & (j0 >= 0) & (j0 < WW);
        gw[n][0] = v00 ? glt : 0.f;   // (i0,j0)
        gw[n][1] = v11 ? grb : 0.f;   // (i1,j1)
        gw[n][2] = v01 ? glb : 0.f;   // (i0,j1)
        gw[n][3] = v10 ? grt : 0.f;   // (i1,j0)
        bool okr0 = ((i0 >= h - 2) & (i0 <= h + 3)) | !(v00 | v01);
        bool okr1 = ((i1 >= h - 2) & (i1 <= h + 3)) | !(v11 | v10);
        bool ok = okr0 & okr1;
        if (ok) okmask |= (1u << n);
        int r0w = min(max(i0 - (h - 2), 0), WROWS - 1);
        int r1w = min(max(i1 - (h - 2), 0), WROWS - 1);
        int r0g = min(max(i0, 0), HH - 1);
        int r1g = min(max(i1, 0), HH - 1);
        int j0c = min(max(j0, 0), WW - 1);
        int j1c = min(max(j1, 0), WW - 1);
        po[n]  = ok ? (r0w * WW + j0c) : (r0g * WW + j0c);
        pdr[n] = ok ? (r1w - r0w) * WW : (r1g - r0g) * WW;
        pdj[n] = j1c - j0c;
    }

    // ================= PASS B: main GEMM (M=64, N=256, K=1152) ==============
    f32x4 acc[4][4];
    #pragma unroll
    for (int mi = 0; mi < 4; ++mi)
        #pragma unroll
        for (int ni = 0; ni < 4; ++ni)
            acc[mi][ni] = (f32x4){0.f, 0.f, 0.f, 0.f};

    int oc0 = wv * 64;

    for (int cb = 0; cb < 4; ++cb) {
        for (int s = 0; s < 4; ++s) {
            __syncthreads();                 // param/win readers done (s==0: +MFMA Atile readers)
            commit_stage(ov, pf, tid);
            __syncthreads();                 // win ready
            {
                int ns = s + 1, nc = cb;
                if (ns == 4) { ns = 0; ++nc; }
                if (nc < 4) pf = issue_stage(xb, h, nc, ns, tid);
            }
            #pragma unroll
            for (int ci = 0; ci < 2; ++ci) {
                int wc  = wv * 2 + ci;
                int c32 = s * 8 + wc;
                const float* winc = ov + wc * WINF;
                const float* xg   = xb + (size_t)(cb * 32 + c32) * HW;
                #pragma unroll
                for (int n = 0; n < NPTS; ++n) {
                    int o = po[n], d1 = pdr[n], d2 = pdj[n];
                    float x00, x01, x10, x11;
                    if (okmask & (1u << n)) {
                        x00 = winc[o];
                        x01 = winc[o + d2];
                        x10 = winc[o + d1];
                        x11 = winc[o + d1 + d2];
                    } else {                 // rare: corner outside 6-row window
                        x00 = xg[o];
                        x01 = xg[o + d2];
                        x10 = xg[o + d1];
                        x11 = xg[o + d1 + d2];
                    }
                    float v =       gw[n][0] * x00;
                    v = fmaf(gw[n][1], x11, v);
                    v = fmaf(gw[n][2], x01, v);
                    v = fmaf(gw[n][3], x10, v);
                    Atile[spix][c32 * 9 + n] = f2bf(v);
                }
            }
        }
        __syncthreads();                     // Atile complete
        for (int q = 0; q < 9; ++q) {
            int koff = q * 32 + kg * 8;
            bf16x8 af[4];
            #pragma unroll
            for (int mi = 0; mi < 4; ++mi)
                af[mi] = *(const bf16x8*)&Atile[mi * 16 + l15][koff];
            #pragma unroll
            for (int ni = 0; ni < 4; ++ni) {
                int oc = oc0 + ni * 16 + l15;
                bf16x8 bfr = loadw8(w_conv + (size_t)oc * KTOT + cb * BK + koff);
                #pragma unroll
                for (int mi = 0; mi < 4; ++mi)
                    acc[mi][ni] = __builtin_amdgcn_mfma_f32_16x16x32_bf16(af[mi], bfr, acc[mi][ni], 0, 0, 0);
            }
        }
    }

    // ================= epilogue: BN + ReLU, float4 stores ===================
    #pragma unroll
    for (int ni = 0; ni < 4; ++ni) {
        int oc = oc0 + ni * 16 + l15;
        float inv   = 1.f / sqrtf(bn_var[oc] + 1e-5f);
        float scale = bn_gamma[oc] * inv;
        float shift = bn_beta[oc] - bn_mean[oc] * scale;
        float* op = out + ((size_t)b * OUTC + oc) * HW + h * WW + kg * 4;
        #pragma unroll
        for (int mi = 0; mi < 4; ++mi) {
            f32x4 o4;
            #pragma unroll
            for (int j = 0; j < 4; ++j) {
                float v = fmaf(acc[mi][ni][j], scale, shift);
                o4[j] = v > 0.f ? v : 0.f;
            }
            *(f32x4*)(op + mi * 16) = o4;
        }
    }
}

extern "C" void kernel_launch(void* const* d_in, const int* in_sizes, int n_in,
                              void* d_out, int out_size, void* d_ws, size_t ws_size,
                              hipStream_t stream) {
    (void)in_sizes; (void)n_in; (void)out_size; (void)d_ws; (void)ws_size;
    const float* x        = (const float*)d_in[0];
    const float* w_offset = (const float*)d_in[1];
    const float* b_offset = (const float*)d_in[2];
    const float* w_mask   = (const float*)d_in[3];
    const float* b_mask   = (const float*)d_in[4];
    const float* w_conv   = (const float*)d_in[5];
    const float* bn_gamma = (const float*)d_in[6];
    const float* bn_beta  = (const float*)d_in[7];
    const float* bn_mean  = (const float*)d_in[8];
    const float* bn_var   = (const float*)d_in[9];
    float* out = (float*)d_out;

    fused_kernel<<<BB * HH, 256, 0, stream>>>(x, w_offset, b_offset, w_mask, b_mask,
                                              w_conv, bn_gamma, bn_beta, bn_mean, bn_var,
                                              out);
}

// Round 7
// 178.423 us; speedup vs baseline: 4.4845x; 2.8082x over previous
//
#include <hip/hip_runtime.h>
#include <math.h>

#define BB 8
#define CC 128
#define HH 64
#define WW 64
#define NPTS 9
#define OUTC 256
#define HW (HH*WW)
#define KTOT (CC*NPTS)   // 1152
#define BK 288           // 32 channels * 9 taps per K-chunk
#define AP 290           // Atile row in bf16 elems: 580 B = 145 words (ODD -> 2-way=free)
#define WROWS 6          // x row window: global rows h-2 .. h+3
#define WINF (WROWS*WW)  // 384 floats per staged channel
#define NCH 16           // channels staged per phase (512 threads)

typedef __attribute__((ext_vector_type(8))) short bf16x8;
typedef __attribute__((ext_vector_type(4))) float f32x4;

__device__ __forceinline__ unsigned short f2bf(float f) {
    unsigned int u = __builtin_bit_cast(unsigned int, f);
    unsigned int r = (u + 0x7FFFu + ((u >> 16) & 1u)) >> 16;   // RNE
    return (unsigned short)r;
}

__device__ __forceinline__ bf16x8 loadw8(const float* p) {
    const float4* p4 = (const float4*)p;
    float4 lo = p4[0], hi = p4[1];
    bf16x8 r;
    r[0] = (short)f2bf(lo.x); r[1] = (short)f2bf(lo.y);
    r[2] = (short)f2bf(lo.z); r[3] = (short)f2bf(lo.w);
    r[4] = (short)f2bf(hi.x); r[5] = (short)f2bf(hi.y);
    r[6] = (short)f2bf(hi.z); r[7] = (short)f2bf(hi.w);
    return r;
}

// Stage 16 channels x 6 rows x 64 cols of x (f32) into LDS window.
__device__ __forceinline__ void stage_win16(float* winp, const float* __restrict__ xb,
                                            int h, int cb, int s, int tid) {
    int c8 = tid >> 5, sub = tid & 31;               // c8: 0..15
    const float* xc = xb + (size_t)(cb * 32 + s * NCH + c8) * HW;
    float* wr = winp + c8 * WINF + sub * 4;
    float4 z = make_float4(0.f, 0.f, 0.f, 0.f);
    int e0 = sub * 4;
    int gr0 = h - 2 + (e0 >> 6);
    int gr1 = h - 2 + ((e0 + 128) >> 6);
    int gr2 = h - 2 + ((e0 + 256) >> 6);
    *(float4*)(wr)       = (gr0 >= 0 && gr0 < HH) ? *(const float4*)(xc + gr0 * WW + (e0 & 63)) : z;
    *(float4*)(wr + 128) = (gr1 >= 0 && gr1 < HH) ? *(const float4*)(xc + gr1 * WW + ((e0 + 128) & 63)) : z;
    *(float4*)(wr + 256) = (gr2 >= 0 && gr2 < HH) ? *(const float4*)(xc + gr2 * WW + ((e0 + 256) & 63)) : z;
}

// 512 threads = 8 waves; grid 512 -> 2 blocks/CU, 16 waves/CU.
// Register budget: params live in LDS (not regs); acc[4][2]=32 VGPR persistent.
// (512,4) caps VGPR at 128 -- R5/R6 lesson: spills are catastrophic, so the
// design keeps natural demand well under the cap (~90).
__global__ __launch_bounds__(512, 4) void fused_kernel(
    const float* __restrict__ x,
    const float* __restrict__ w_offset, const float* __restrict__ b_offset,
    const float* __restrict__ w_mask,   const float* __restrict__ b_mask,
    const float* __restrict__ w_conv,
    const float* __restrict__ bn_gamma, const float* __restrict__ bn_beta,
    const float* __restrict__ bn_mean,  const float* __restrict__ bn_var,
    float* __restrict__ out)
{
    __shared__ unsigned short Atile[64][AP];     // 37120 B
    __shared__ float ov[NCH * WINF];             // 24576 B: win; px/py/m overlay at base
    __shared__ float params[NPTS][5][64];        // 11520 B: gw0..3, packed idx
    // total 73216 B -> 2 blocks/CU

    int blk = blockIdx.x;
    int b = blk >> 6, h = blk & 63;
    int tid  = threadIdx.x;
    int lane = tid & 63;
    int wv   = __builtin_amdgcn_readfirstlane(tid >> 6);  // wave 0..7
    int l15  = lane & 15;
    int kg   = lane >> 4;
    int spix = lane;                                      // pixel for build phases

    const float* xb = x + (size_t)b * CC * HW;

    // ================= PASS A: offset/mask conv (M=64,N=32,K=1152) =========
    // wave wv: M-frag mi_a = wv&3 (pixel rows), N-frag nf_a = wv>>2 (cols 0-15/16-31)
    int mi_a = wv & 3, nf_a = wv >> 2;
    f32x4 s1acc = {0.f, 0.f, 0.f, 0.f};

    for (int cb = 0; cb < 4; ++cb) {
        for (int s = 0; s < 2; ++s) {
            __syncthreads();                 // win readers (+ Atile readers at s==0) done
            stage_win16(ov, xb, h, cb, s, tid);
            __syncthreads();                 // win ready
            #pragma unroll
            for (int ci = 0; ci < 2; ++ci) {
                int wc  = wv * 2 + ci;       // staged channel 0..15
                int c32 = s * NCH + wc;      // channel within cb (0..31)
                const float* wrow = ov + wc * WINF;
                #pragma unroll
                for (int ky = 0; ky < 3; ++ky) {
                    #pragma unroll
                    for (int kx = 0; kx < 3; ++kx) {
                        int col  = spix + kx - 1;
                        int colc = min(max(col, 0), WW - 1);
                        float v = wrow[(ky + 1) * WW + colc];  // global row h+ky-1
                        v = (col >= 0 && col < WW) ? v : 0.f;
                        Atile[spix][c32 * 9 + ky * 3 + kx] = f2bf(v);
                    }
                }
            }
        }
        __syncthreads();                     // Atile complete
        for (int q = 0; q < 9; ++q) {
            int koff  = q * 32 + kg * 8;
            int kglob = cb * BK + koff;
            bf16x8 af = *(const bf16x8*)&Atile[mi_a * 16 + l15][koff];
            int nn = nf_a * 16 + l15;
            const float* wp = (nn < 18)
                ? (w_offset + (size_t)nn * KTOT + kglob)
                : (w_mask + (size_t)(nn < 27 ? nn - 18 : 0) * KTOT + kglob);
            bf16x8 bfr = loadw8(wp);
            if (nn >= 27) {
                #pragma unroll
                for (int e = 0; e < 8; ++e) bfr[e] = 0;
            }
            s1acc = __builtin_amdgcn_mfma_f32_16x16x32_bf16(af, bfr, s1acc, 0, 0, 0);
        }
    }

    // ---- pass-A epilogue into ov overlay (win dead) ------------------------
    // px at ov[0..575], py at ov[576..1151], m at ov[1152..1727]
    #pragma unroll
    for (int j = 0; j < 4; ++j) {
        float val = s1acc[j];
        int nn   = nf_a * 16 + l15;
        int pixl = mi_a * 16 + kg * 4 + j;
        if (nn < 9) {
            ov[nn * 64 + pixl] = val + b_offset[nn] + (float)(nn / 3 - 1) + (float)(h + 1);
        } else if (nn < 18) {
            int n = nn - 9;
            ov[576 + n * 64 + pixl] = val + b_offset[nn] + (float)(n % 3 - 1) + (float)(pixl + 1);
        } else if (nn < 27) {
            int n = nn - 18;
            float sg = val + b_mask[n];
            ov[1152 + n * 64 + pixl] = 1.f / (1.f + expf(-sg));
        }
    }
    __syncthreads();

    // ================= param table: 64 threads, results to LDS ==============
    // pk: bits0-12 o | bits13-19 (drow+64) | bits20-26 (dcol+64) | bit27 ok
    if (tid < 64) {
        int t = tid;
        #pragma unroll
        for (int n = 0; n < NPTS; ++n) {
            float px = ov[n * 64 + t];
            float py = ov[576 + n * 64 + t];
            float m  = ov[1152 + n * 64 + t];
            float fx = floorf(px), fy = floorf(py);
            float qltx = fminf(fmaxf(fx,       0.f), 65.f);
            float qlty = fminf(fmaxf(fy,       0.f), 65.f);
            float qrbx = fminf(fmaxf(fx + 1.f, 0.f), 65.f);
            float qrby = fminf(fmaxf(fy + 1.f, 0.f), 65.f);
            float pxc  = fminf(fmaxf(px, 0.f), 65.f);
            float pyc  = fminf(fmaxf(py, 0.f), 65.f);
            float glt = (1.f + (qltx - pxc)) * (1.f + (qlty - pyc)) * m;
            float grb = (1.f - (qrbx - pxc)) * (1.f - (qrby - pyc)) * m;
            float glb = (1.f + (qltx - pxc)) * (1.f - (qrby - pyc)) * m;
            float grt = (1.f - (qrbx - pxc)) * (1.f + (qlty - pyc)) * m;
            int i0 = (int)qltx - 1, j0 = (int)qlty - 1;
            int i1 = (int)qrbx - 1, j1 = (int)qrby - 1;
            bool v00 = (i0 >= 0) & (i0 < HH) & (j0 >= 0) & (j0 < WW);
            bool v11 = (i1 >= 0) & (i1 < HH) & (j1 >= 0) & (j1 < WW);
            bool v01 = (i0 >= 0) & (i0 < HH) & (j1 >= 0) & (j1 < WW);
            bool v10 = (i1 >= 0) & (i1 < HH) & (j0 >= 0) & (j0 < WW);
            params[n][0][t] = v00 ? glt : 0.f;   // (i0,j0)
            params[n][1][t] = v11 ? grb : 0.f;   // (i1,j1)
            params[n][2][t] = v01 ? glb : 0.f;   // (i0,j1)
            params[n][3][t] = v10 ? grt : 0.f;   // (i1,j0)
            bool okr0 = ((i0 >= h - 2) & (i0 <= h + 3)) | !(v00 | v01);
            bool okr1 = ((i1 >= h - 2) & (i1 <= h + 3)) | !(v11 | v10);
            bool ok = okr0 & okr1;
            int r0w = min(max(i0 - (h - 2), 0), WROWS - 1);
            int r1w = min(max(i1 - (h - 2), 0), WROWS - 1);
            int r0g = min(max(i0, 0), HH - 1);
            int r1g = min(max(i1, 0), HH - 1);
            int j0c = min(max(j0, 0), WW - 1);
            int j1c = min(max(j1, 0), WW - 1);
            int o  = ok ? (r0w * WW + j0c) : (r0g * WW + j0c);
            int dr = ok ? (r1w - r0w) : (r1g - r0g);
            int dj = j1c - j0c;
            unsigned pk = (unsigned)o | ((unsigned)(dr + 64) << 13)
                        | ((unsigned)(dj + 64) << 20) | ((unsigned)ok << 27);
            params[n][4][t] = __builtin_bit_cast(float, pk);
        }
    }
    __syncthreads();

    // ================= PASS B: main GEMM (M=64, N=256, K=1152) ==============
    f32x4 acc[4][2];
    #pragma unroll
    for (int mi = 0; mi < 4; ++mi)
        #pragma unroll
        for (int ni = 0; ni < 2; ++ni)
            acc[mi][ni] = (f32x4){0.f, 0.f, 0.f, 0.f};

    int oc0 = wv * 32;

    for (int cb = 0; cb < 4; ++cb) {
        for (int s = 0; s < 2; ++s) {
            __syncthreads();                 // param/win readers (+ MFMA Atile readers at s==0) done
            stage_win16(ov, xb, h, cb, s, tid);
            __syncthreads();                 // win ready
            int wc0  = wv * 2;
            int c32a = s * NCH + wc0, c32b = c32a + 1;
            const float* winA = ov + wc0 * WINF;
            const float* winB = winA + WINF;
            const float* xgA  = xb + (size_t)(cb * 32 + c32a) * HW;
            const float* xgB  = xgA + HW;
            #pragma unroll
            for (int n = 0; n < NPTS; ++n) {
                float g0 = params[n][0][spix];
                float g1 = params[n][1][spix];
                float g2 = params[n][2][spix];
                float g3 = params[n][3][spix];
                unsigned pk = __builtin_bit_cast(unsigned, params[n][4][spix]);
                int o  = pk & 0x1FFF;
                int d1 = ((int)((pk >> 13) & 0x7F) - 64) * WW;
                int d2 = (int)((pk >> 20) & 0x7F) - 64;
                const float* pa;
                const float* pb;
                if (pk & (1u << 27)) { pa = winA; pb = winB; }
                else                 { pa = xgA;  pb = xgB;  }   // rare fallback
                float v0 =       g0 * pa[o];
                v0 = fmaf(g1, pa[o + d1 + d2], v0);
                v0 = fmaf(g2, pa[o + d2],      v0);
                v0 = fmaf(g3, pa[o + d1],      v0);
                Atile[spix][c32a * 9 + n] = f2bf(v0);
                float v1 =       g0 * pb[o];
                v1 = fmaf(g1, pb[o + d1 + d2], v1);
                v1 = fmaf(g2, pb[o + d2],      v1);
                v1 = fmaf(g3, pb[o + d1],      v1);
                Atile[spix][c32b * 9 + n] = f2bf(v1);
            }
        }
        __syncthreads();                     // Atile complete
        for (int q = 0; q < 9; ++q) {
            int koff = q * 32 + kg * 8;
            bf16x8 af[4];
            #pragma unroll
            for (int mi = 0; mi < 4; ++mi)
                af[mi] = *(const bf16x8*)&Atile[mi * 16 + l15][koff];
            #pragma unroll
            for (int ni = 0; ni < 2; ++ni) {
                int oc = oc0 + ni * 16 + l15;
                bf16x8 bfr = loadw8(w_conv + (size_t)oc * KTOT + cb * BK + koff);
                #pragma unroll
                for (int mi = 0; mi < 4; ++mi)
                    acc[mi][ni] = __builtin_amdgcn_mfma_f32_16x16x32_bf16(af[mi], bfr, acc[mi][ni], 0, 0, 0);
            }
        }
    }

    // ================= epilogue: BN + ReLU, float4 stores ===================
    #pragma unroll
    for (int ni = 0; ni < 2; ++ni) {
        int oc = oc0 + ni * 16 + l15;
        float inv   = 1.f / sqrtf(bn_var[oc] + 1e-5f);
        float scale = bn_gamma[oc] * inv;
        float shift = bn_beta[oc] - bn_mean[oc] * scale;
        float* op = out + ((size_t)b * OUTC + oc) * HW + h * WW + kg * 4;
        #pragma unroll
        for (int mi = 0; mi < 4; ++mi) {
            f32x4 o4;
            #pragma unroll
            for (int j = 0; j < 4; ++j) {
                float v = fmaf(acc[mi][ni][j], scale, shift);
                o4[j] = v > 0.f ? v : 0.f;
            }
            *(f32x4*)(op + mi * 16) = o4;
        }
    }
}

extern "C" void kernel_launch(void* const* d_in, const int* in_sizes, int n_in,
                              void* d_out, int out_size, void* d_ws, size_t ws_size,
                              hipStream_t stream) {
    (void)in_sizes; (void)n_in; (void)out_size; (void)d_ws; (void)ws_size;
    const float* x        = (const float*)d_in[0];
    const float* w_offset = (const float*)d_in[1];
    const float* b_offset = (const float*)d_in[2];
    const float* w_mask   = (const float*)d_in[3];
    const float* b_mask   = (const float*)d_in[4];
    const float* w_conv   = (const float*)d_in[5];
    const float* bn_gamma = (const float*)d_in[6];
    const float* bn_beta  = (const float*)d_in[7];
    const float* bn_mean  = (const float*)d_in[8];
    const float* bn_var   = (const float*)d_in[9];
    float* out = (float*)d_out;

    fused_kernel<<<BB * HH, 512, 0, stream>>>(x, w_offset, b_offset, w_mask, b_mask,
                                              w_conv, bn_gamma, bn_beta, bn_mean, bn_var,
                                              out);
}

// Round 8
// 166.733 us; speedup vs baseline: 4.7989x; 1.0701x over previous
//
#include <hip/hip_runtime.h>
#include <math.h>

#define BB 8
#define CC 128
#define HH 64
#define WW 64
#define NPTS 9
#define OUTC 256
#define HW (HH*WW)
#define KTOT (CC*NPTS)   // 1152
#define BK 288           // 32 channels * 9 taps per K-chunk
#define AP 290           // Atile row in bf16 elems: 580 B = 145 words (ODD -> 2-way=free)
#define WROWS 6          // x row window: global rows h-2 .. h+3
#define WINF (WROWS*WW)  // 384 floats per staged channel
#define NCH 16           // channels staged per phase (512 threads)

typedef __attribute__((ext_vector_type(8))) short bf16x8;
typedef __attribute__((ext_vector_type(4))) float f32x4;

__device__ __forceinline__ unsigned short f2bf(float f) {
    unsigned int u = __builtin_bit_cast(unsigned int, f);
    unsigned int r = (u + 0x7FFFu + ((u >> 16) & 1u)) >> 16;   // RNE
    return (unsigned short)r;
}

__device__ __forceinline__ bf16x8 loadw8(const float* p) {
    const float4* p4 = (const float4*)p;
    float4 lo = p4[0], hi = p4[1];
    bf16x8 r;
    r[0] = (short)f2bf(lo.x); r[1] = (short)f2bf(lo.y);
    r[2] = (short)f2bf(lo.z); r[3] = (short)f2bf(lo.w);
    r[4] = (short)f2bf(hi.x); r[5] = (short)f2bf(hi.y);
    r[6] = (short)f2bf(hi.z); r[7] = (short)f2bf(hi.w);
    return r;
}

// T14 async-stage split for the 16-channel window (512 threads: c8=0..15).
struct PF { float4 v0, v1, v2; };

__device__ __forceinline__ PF issue16(const float* __restrict__ xb,
                                      int h, int cb, int s, int tid) {
    int c8 = tid >> 5, sub = tid & 31;
    const float* xc = xb + (size_t)(cb * 32 + s * NCH + c8) * HW;
    float4 z = make_float4(0.f, 0.f, 0.f, 0.f);
    PF p;
    int e0 = sub * 4;
    int gr0 = h - 2 + (e0 >> 6);
    int gr1 = h - 2 + ((e0 + 128) >> 6);
    int gr2 = h - 2 + ((e0 + 256) >> 6);
    p.v0 = (gr0 >= 0 && gr0 < HH) ? *(const float4*)(xc + gr0 * WW + (e0 & 63)) : z;
    p.v1 = (gr1 >= 0 && gr1 < HH) ? *(const float4*)(xc + gr1 * WW + ((e0 + 128) & 63)) : z;
    p.v2 = (gr2 >= 0 && gr2 < HH) ? *(const float4*)(xc + gr2 * WW + ((e0 + 256) & 63)) : z;
    return p;
}

__device__ __forceinline__ void commit16(float* winp, const PF& p, int tid) {
    int c8 = tid >> 5, sub = tid & 31;
    float* wr = winp + c8 * WINF + sub * 4;
    *(float4*)(wr)       = p.v0;
    *(float4*)(wr + 128) = p.v1;
    *(float4*)(wr + 256) = p.v2;
}

// 512 threads = 8 waves; grid 512 -> 2 blocks/CU (LDS-capped), 16 waves/CU.
// waves_per_eu(4,4): hardware occupancy is LDS-capped at 4 waves/EU, so pin
// the allocator budget to 512/4 = 128 VGPRs. R7 lesson: without the max, the
// allocator squeezed to the 64 tier and spilled (WRITE_SIZE 43->207 MB).
__global__ __launch_bounds__(512) __attribute__((amdgpu_waves_per_eu(4, 4)))
void fused_kernel(
    const float* __restrict__ x,
    const float* __restrict__ w_offset, const float* __restrict__ b_offset,
    const float* __restrict__ w_mask,   const float* __restrict__ b_mask,
    const float* __restrict__ w_conv,
    const float* __restrict__ bn_gamma, const float* __restrict__ bn_beta,
    const float* __restrict__ bn_mean,  const float* __restrict__ bn_var,
    float* __restrict__ out)
{
    __shared__ unsigned short Atile[64][AP];     // 37120 B
    __shared__ float ov[NCH * WINF];             // 24576 B: win; px/py/m overlay at base
    __shared__ float params[NPTS][5][64];        // 11520 B: gw0..3, packed idx
    // total 73216 B -> 2 blocks/CU

    int blk = blockIdx.x;
    int b = blk >> 6, h = blk & 63;
    int tid  = threadIdx.x;
    int lane = tid & 63;
    int wv   = __builtin_amdgcn_readfirstlane(tid >> 6);  // wave 0..7
    int l15  = lane & 15;
    int kg   = lane >> 4;
    int spix = lane;                                      // pixel for build phases

    const float* xb = x + (size_t)b * CC * HW;

    // ================= PASS A: offset/mask conv (M=64,N=32,K=1152) =========
    // wave wv: M-frag mi_a = wv&3 (pixel rows), N-frag nf_a = wv>>2
    int mi_a = wv & 3, nf_a = wv >> 2;
    f32x4 s1acc = {0.f, 0.f, 0.f, 0.f};

    PF pf = issue16(xb, h, 0, 0, tid);
    for (int cb = 0; cb < 4; ++cb) {
        for (int s = 0; s < 2; ++s) {
            __syncthreads();                 // win readers (+ Atile readers at s==0) done
            commit16(ov, pf, tid);
            __syncthreads();                 // win ready
            {   // prefetch next phase (wraps into pass B's (0,0) at the end)
                int ns = s + 1, nc = cb;
                if (ns == 2) { ns = 0; ++nc; }
                if (nc == 4) { nc = 0; ns = 0; }
                pf = issue16(xb, h, nc, ns, tid);
            }
            #pragma unroll
            for (int ci = 0; ci < 2; ++ci) {
                int wc  = wv * 2 + ci;       // staged channel 0..15
                int c32 = s * NCH + wc;      // channel within cb (0..31)
                const float* wrow = ov + wc * WINF;
                #pragma unroll
                for (int ky = 0; ky < 3; ++ky) {
                    #pragma unroll
                    for (int kx = 0; kx < 3; ++kx) {
                        int col  = spix + kx - 1;
                        int colc = min(max(col, 0), WW - 1);
                        float v = wrow[(ky + 1) * WW + colc];  // global row h+ky-1
                        v = (col >= 0 && col < WW) ? v : 0.f;
                        Atile[spix][c32 * 9 + ky * 3 + kx] = f2bf(v);
                    }
                }
            }
        }
        __syncthreads();                     // Atile complete
        for (int q = 0; q < 9; ++q) {
            int koff  = q * 32 + kg * 8;
            int kglob = cb * BK + koff;
            bf16x8 af = *(const bf16x8*)&Atile[mi_a * 16 + l15][koff];
            int nn = nf_a * 16 + l15;
            const float* wp = (nn < 18)
                ? (w_offset + (size_t)nn * KTOT + kglob)
                : (w_mask + (size_t)(nn < 27 ? nn - 18 : 0) * KTOT + kglob);
            bf16x8 bfr = loadw8(wp);
            if (nn >= 27) {
                #pragma unroll
                for (int e = 0; e < 8; ++e) bfr[e] = 0;
            }
            s1acc = __builtin_amdgcn_mfma_f32_16x16x32_bf16(af, bfr, s1acc, 0, 0, 0);
        }
    }

    // ---- pass-A epilogue into ov overlay (win dead) ------------------------
    // px at ov[0..575], py at ov[576..1151], m at ov[1152..1727]
    #pragma unroll
    for (int j = 0; j < 4; ++j) {
        float val = s1acc[j];
        int nn   = nf_a * 16 + l15;
        int pixl = mi_a * 16 + kg * 4 + j;
        if (nn < 9) {
            ov[nn * 64 + pixl] = val + b_offset[nn] + (float)(nn / 3 - 1) + (float)(h + 1);
        } else if (nn < 18) {
            int n = nn - 9;
            ov[576 + n * 64 + pixl] = val + b_offset[nn] + (float)(n % 3 - 1) + (float)(pixl + 1);
        } else if (nn < 27) {
            int n = nn - 18;
            float sg = val + b_mask[n];
            ov[1152 + n * 64 + pixl] = 1.f / (1.f + expf(-sg));
        }
    }
    __syncthreads();

    // ================= param table: 64 threads, results to LDS ==============
    // pk: bits0-12 o | bits13-19 (drow+64) | bits20-26 (dcol+64) | bit27 ok
    if (tid < 64) {
        int t = tid;
        #pragma unroll
        for (int n = 0; n < NPTS; ++n) {
            float px = ov[n * 64 + t];
            float py = ov[576 + n * 64 + t];
            float m  = ov[1152 + n * 64 + t];
            float fx = floorf(px), fy = floorf(py);
            float qltx = fminf(fmaxf(fx,       0.f), 65.f);
            float qlty = fminf(fmaxf(fy,       0.f), 65.f);
            float qrbx = fminf(fmaxf(fx + 1.f, 0.f), 65.f);
            float qrby = fminf(fmaxf(fy + 1.f, 0.f), 65.f);
            float pxc  = fminf(fmaxf(px, 0.f), 65.f);
            float pyc  = fminf(fmaxf(py, 0.f), 65.f);
            float glt = (1.f + (qltx - pxc)) * (1.f + (qlty - pyc)) * m;
            float grb = (1.f - (qrbx - pxc)) * (1.f - (qrby - pyc)) * m;
            float glb = (1.f + (qltx - pxc)) * (1.f - (qrby - pyc)) * m;
            float grt = (1.f - (qrbx - pxc)) * (1.f + (qlty - pyc)) * m;
            int i0 = (int)qltx - 1, j0 = (int)qlty - 1;
            int i1 = (int)qrbx - 1, j1 = (int)qrby - 1;
            bool v00 = (i0 >= 0) & (i0 < HH) & (j0 >= 0) & (j0 < WW);
            bool v11 = (i1 >= 0) & (i1 < HH) & (j1 >= 0) & (j1 < WW);
            bool v01 = (i0 >= 0) & (i0 < HH) & (j1 >= 0) & (j1 < WW);
            bool v10 = (i1 >= 0) & (i1 < HH) & (j0 >= 0) & (j0 < WW);
            params[n][0][t] = v00 ? glt : 0.f;   // (i0,j0)
            params[n][1][t] = v11 ? grb : 0.f;   // (i1,j1)
            params[n][2][t] = v01 ? glb : 0.f;   // (i0,j1)
            params[n][3][t] = v10 ? grt : 0.f;   // (i1,j0)
            bool okr0 = ((i0 >= h - 2) & (i0 <= h + 3)) | !(v00 | v01);
            bool okr1 = ((i1 >= h - 2) & (i1 <= h + 3)) | !(v11 | v10);
            bool ok = okr0 & okr1;
            int r0w = min(max(i0 - (h - 2), 0), WROWS - 1);
            int r1w = min(max(i1 - (h - 2), 0), WROWS - 1);
            int r0g = min(max(i0, 0), HH - 1);
            int r1g = min(max(i1, 0), HH - 1);
            int j0c = min(max(j0, 0), WW - 1);
            int j1c = min(max(j1, 0), WW - 1);
            int o  = ok ? (r0w * WW + j0c) : (r0g * WW + j0c);
            int dr = ok ? (r1w - r0w) : (r1g - r0g);
            int dj = j1c - j0c;
            unsigned pk = (unsigned)o | ((unsigned)(dr + 64) << 13)
                        | ((unsigned)(dj + 64) << 20) | ((unsigned)ok << 27);
            params[n][4][t] = __builtin_bit_cast(float, pk);
        }
    }
    __syncthreads();

    // ================= PASS B: main GEMM (M=64, N=256, K=1152) ==============
    f32x4 acc[4][2];
    #pragma unroll
    for (int mi = 0; mi < 4; ++mi)
        #pragma unroll
        for (int ni = 0; ni < 2; ++ni)
            acc[mi][ni] = (f32x4){0.f, 0.f, 0.f, 0.f};

    int oc0 = wv * 32;

    for (int cb = 0; cb < 4; ++cb) {
        for (int s = 0; s < 2; ++s) {
            __syncthreads();                 // param/win readers (+ MFMA Atile readers at s==0) done
            commit16(ov, pf, tid);
            __syncthreads();                 // win ready
            {
                int ns = s + 1, nc = cb;
                if (ns == 2) { ns = 0; ++nc; }
                if (nc < 4) pf = issue16(xb, h, nc, ns, tid);
            }
            int wc0  = wv * 2;
            int c32a = s * NCH + wc0, c32b = c32a + 1;
            const float* winA = ov + wc0 * WINF;
            const float* winB = winA + WINF;
            const float* xgA  = xb + (size_t)(cb * 32 + c32a) * HW;
            const float* xgB  = xgA + HW;
            #pragma unroll
            for (int n = 0; n < NPTS; ++n) {
                float g0 = params[n][0][spix];
                float g1 = params[n][1][spix];
                float g2 = params[n][2][spix];
                float g3 = params[n][3][spix];
                unsigned pk = __builtin_bit_cast(unsigned, params[n][4][spix]);
                int o  = pk & 0x1FFF;
                int d1 = ((int)((pk >> 13) & 0x7F) - 64) * WW;
                int d2 = (int)((pk >> 20) & 0x7F) - 64;
                // explicit dual path: LDS side compiles to ds_read, global side
                // (execz-skipped in practice) to global_load. NO pointer select
                // across address spaces (R7: flat-load + traffic blowup).
                float a00, a01, a10, a11, b00, b01, b10, b11;
                if (pk & (1u << 27)) {
                    a00 = winA[o];           b00 = winB[o];
                    a11 = winA[o + d1 + d2]; b11 = winB[o + d1 + d2];
                    a01 = winA[o + d2];      b01 = winB[o + d2];
                    a10 = winA[o + d1];      b10 = winB[o + d1];
                } else {                     // rare: corner outside 6-row window
                    a00 = xgA[o];            b00 = xgB[o];
                    a11 = xgA[o + d1 + d2];  b11 = xgB[o + d1 + d2];
                    a01 = xgA[o + d2];       b01 = xgB[o + d2];
                    a10 = xgA[o + d1];       b10 = xgB[o + d1];
                }
                float v0 =       g0 * a00;
                v0 = fmaf(g1, a11, v0);
                v0 = fmaf(g2, a01, v0);
                v0 = fmaf(g3, a10, v0);
                Atile[spix][c32a * 9 + n] = f2bf(v0);
                float v1 =       g0 * b00;
                v1 = fmaf(g1, b11, v1);
                v1 = fmaf(g2, b01, v1);
                v1 = fmaf(g3, b10, v1);
                Atile[spix][c32b * 9 + n] = f2bf(v1);
            }
        }
        __syncthreads();                     // Atile complete
        for (int q = 0; q < 9; ++q) {
            int koff = q * 32 + kg * 8;
            bf16x8 af[4];
            #pragma unroll
            for (int mi = 0; mi < 4; ++mi)
                af[mi] = *(const bf16x8*)&Atile[mi * 16 + l15][koff];
            #pragma unroll
            for (int ni = 0; ni < 2; ++ni) {
                int oc = oc0 + ni * 16 + l15;
                bf16x8 bfr = loadw8(w_conv + (size_t)oc * KTOT + cb * BK + koff);
                #pragma unroll
                for (int mi = 0; mi < 4; ++mi)
                    acc[mi][ni] = __builtin_amdgcn_mfma_f32_16x16x32_bf16(af[mi], bfr, acc[mi][ni], 0, 0, 0);
            }
        }
    }

    // ================= epilogue: BN + ReLU, float4 stores ===================
    #pragma unroll
    for (int ni = 0; ni < 2; ++ni) {
        int oc = oc0 + ni * 16 + l15;
        float inv   = 1.f / sqrtf(bn_var[oc] + 1e-5f);
        float scale = bn_gamma[oc] * inv;
        float shift = bn_beta[oc] - bn_mean[oc] * scale;
        float* op = out + ((size_t)b * OUTC + oc) * HW + h * WW + kg * 4;
        #pragma unroll
        for (int mi = 0; mi < 4; ++mi) {
            f32x4 o4;
            #pragma unroll
            for (int j = 0; j < 4; ++j) {
                float v = fmaf(acc[mi][ni][j], scale, shift);
                o4[j] = v > 0.f ? v : 0.f;
            }
            *(f32x4*)(op + mi * 16) = o4;
        }
    }
}

extern "C" void kernel_launch(void* const* d_in, const int* in_sizes, int n_in,
                              void* d_out, int out_size, void* d_ws, size_t ws_size,
                              hipStream_t stream) {
    (void)in_sizes; (void)n_in; (void)out_size; (void)d_ws; (void)ws_size;
    const float* x        = (const float*)d_in[0];
    const float* w_offset = (const float*)d_in[1];
    const float* b_offset = (const float*)d_in[2];
    const float* w_mask   = (const float*)d_in[3];
    const float* b_mask   = (const float*)d_in[4];
    const float* w_conv   = (const float*)d_in[5];
    const float* bn_gamma = (const float*)d_in[6];
    const float* bn_beta  = (const float*)d_in[7];
    const float* bn_mean  = (const float*)d_in[8];
    const float* bn_var   = (const float*)d_in[9];
    float* out = (float*)d_out;

    fused_kernel<<<BB * HH, 512, 0, stream>>>(x, w_offset, b_offset, w_mask, b_mask,
                                              w_conv, bn_gamma, bn_beta, bn_mean, bn_var,
                                              out);
}